// Round 1
// baseline (300.243 us; speedup 1.0000x reference)
//
#include <hip/hip_runtime.h>
#include <stdint.h>

#define SEQ 4096
#define NHEAD 16
#define HDIM 64

typedef __attribute__((ext_vector_type(4))) float f32x4;
typedef __attribute__((ext_vector_type(8))) __bf16 bf16x8;
typedef __attribute__((ext_vector_type(8))) unsigned short u16x8;
typedef __attribute__((ext_vector_type(4))) unsigned short u16x4;

static __device__ __forceinline__ float bf2f(unsigned short u) {
    unsigned int x = ((unsigned int)u) << 16;
    return __builtin_bit_cast(float, x);
}
static __device__ __forceinline__ unsigned short f2bf(float f) {
    unsigned int u = __builtin_bit_cast(unsigned int, f);
    u += 0x7FFFu + ((u >> 16) & 1u);   // RNE
    return (unsigned short)(u >> 16);
}
static __device__ __forceinline__ f32x4 mfma_bf16_16x16x32(u16x8 a, u16x8 b, f32x4 c) {
    return __builtin_amdgcn_mfma_f32_16x16x32_bf16(
        __builtin_bit_cast(bf16x8, a), __builtin_bit_cast(bf16x8, b), c, 0, 0, 0);
}
static __device__ __forceinline__ void gload_lds16(const void* g, void* l) {
    __builtin_amdgcn_global_load_lds(
        (__attribute__((address_space(1))) unsigned int*)g,
        (__attribute__((address_space(3))) unsigned int*)l,
        16, 0, 0);
}

// ---------------- f32 -> bf16 convert ----------------
__global__ void cvt_kernel(const float* __restrict__ src, unsigned short* __restrict__ dst, int n) {
    const int stride = gridDim.x * blockDim.x;
    for (int i = blockIdx.x * blockDim.x + threadIdx.x; i * 4 < n; i += stride) {
        f32x4 v = *(const f32x4*)(src + (size_t)i * 4);
        u16x4 o;
#pragma unroll
        for (int j = 0; j < 4; j++) o[j] = f2bf(v[j]);
        *(u16x4*)(dst + (size_t)i * 4) = o;
    }
}

// ---------------- GEMM: C[M][N] = A[M][K(lda)] * B[N][K]^T ----------------
// 128x128 tile, BK=64, 256 threads = 4 waves (2x2), each wave 64x64 (4x4 frags)
template<int OUT_BF16>
__global__ __launch_bounds__(256) void gemm_bt_kernel(
    const unsigned short* __restrict__ A,
    const unsigned short* __restrict__ B,
    void* __restrict__ Cv,
    int M, int N, int K, int lda)
{
    __shared__ __align__(16) unsigned short As[128 * 64];
    __shared__ __align__(16) unsigned short Bs[128 * 64];
    const int tid = threadIdx.x;
    const int lane = tid & 63;
    const int wave = tid >> 6;
    const int wm = (wave >> 1) * 64;
    const int wn = (wave & 1) * 64;
    const int bm = blockIdx.y * 128, bn = blockIdx.x * 128;
    const int l15 = lane & 15, l4 = lane >> 4;

    f32x4 acc[4][4];
#pragma unroll
    for (int i = 0; i < 4; i++)
#pragma unroll
        for (int j = 0; j < 4; j++) acc[i][j] = (f32x4){0.f, 0.f, 0.f, 0.f};

    const int srow = tid >> 3;
    const int scol = (tid & 7) * 8;
    const unsigned short* Ab = A + (size_t)(bm + srow) * lda + scol;
    const unsigned short* Bb = B + (size_t)(bn + srow) * K + scol;

    for (int kt = 0; kt < K; kt += 64) {
#pragma unroll
        for (int ci = 0; ci < 4; ci++)
            gload_lds16(Ab + (size_t)ci * 32 * lda + kt, &As[ci * 2048 + tid * 8]);
#pragma unroll
        for (int ci = 0; ci < 4; ci++)
            gload_lds16(Bb + (size_t)ci * 32 * K + kt, &Bs[ci * 2048 + tid * 8]);
        __syncthreads();
#pragma unroll
        for (int ks = 0; ks < 2; ks++) {
            const int kc = ks * 32 + l4 * 8;
            u16x8 af[4], bfr[4];
#pragma unroll
            for (int i = 0; i < 4; i++)
                af[i] = *(const u16x8*)&As[(wm + i * 16 + l15) * 64 + kc];
#pragma unroll
            for (int j = 0; j < 4; j++)
                bfr[j] = *(const u16x8*)&Bs[(wn + j * 16 + l15) * 64 + kc];
#pragma unroll
            for (int i = 0; i < 4; i++)
#pragma unroll
                for (int j = 0; j < 4; j++)
                    acc[i][j] = mfma_bf16_16x16x32(af[i], bfr[j], acc[i][j]);
        }
        __syncthreads();
    }

    const int orow = bm + wm + l4 * 4;
    const int ocol = bn + wn + l15;
#pragma unroll
    for (int i = 0; i < 4; i++)
#pragma unroll
        for (int j = 0; j < 4; j++)
#pragma unroll
            for (int r = 0; r < 4; r++) {
                size_t idx = (size_t)(orow + i * 16 + r) * N + (ocol + j * 16);
                if (OUT_BF16) ((unsigned short*)Cv)[idx] = f2bf(acc[i][j][r]);
                else          ((float*)Cv)[idx] = acc[i][j][r];
            }
}

// ---------------- RMS-norm + RoPE + lambda*v ----------------
// one wave = one (t, h) vector of 64 dims; lane = d
__global__ __launch_bounds__(256) void rope_norm_kernel(
    const unsigned short* __restrict__ qkv,   // [SEQ][3072] bf16
    const float* __restrict__ lambdas,
    unsigned short* __restrict__ qh,          // [16][SEQ][64]
    unsigned short* __restrict__ kh,
    unsigned short* __restrict__ vh)
{
    const int lane = threadIdx.x & 63;
    const int wave = threadIdx.x >> 6;
    const int vec = blockIdx.x * 4 + wave;
    const int t = vec >> 4;
    const int h = vec & 15;
    const size_t base = (size_t)t * 3072 + h * 64 + lane;
    float q = bf2f(qkv[base]);
    float k = bf2f(qkv[base + 1024]);
    float v = bf2f(qkv[base + 2048]);
    float sq = q * q, sk = k * k;
#pragma unroll
    for (int m = 1; m < 64; m <<= 1) {
        sq += __shfl_xor(sq, m);
        sk += __shfl_xor(sk, m);
    }
    q *= rsqrtf(sq * (1.0f / 64.0f) + 1e-6f);
    k *= rsqrtf(sk * (1.0f / 64.0f) + 1e-6f);
    const int i = lane & 31;
    // (1/1024)^(i/15) = 2^(-10i/15); zero freq (identity) for i >= 16
    float w = (i < 16) ? exp2f(-(10.0f / 15.0f) * (float)i) : 0.0f;
    float th = (float)t * w;
    float c = cosf(th), s = sinf(th);
    float qp = __shfl_xor(q, 32);
    float kp = __shfl_xor(k, 32);
    float sg = (lane < 32) ? s : -s;   // y1 = x1*c + x2*s ; y2 = x2*c - x1*s
    float qo = q * c + qp * sg;
    float ko = k * c + kp * sg;
    float vo = v * lambdas[0];
    const size_t o = ((size_t)h * SEQ + t) * 64 + lane;
    qh[o] = f2bf(qo);
    kh[o] = f2bf(ko);
    vh[o] = f2bf(vo);
}

// ---------------- V transpose: [h][t][d] -> [h][d][t] ----------------
__global__ __launch_bounds__(256) void transpose_v_kernel(
    const unsigned short* __restrict__ vh, unsigned short* __restrict__ vT)
{
    __shared__ __align__(16) unsigned short tile[64][72];
    const int h = blockIdx.x >> 6;
    const int tt = (blockIdx.x & 63) * 64;
    const int tid = threadIdx.x;
    const int row = tid >> 2;          // 0..63
    const int c0 = (tid & 3) * 16;     // 0,16,32,48
    const u16x8* src = (const u16x8*)(vh + ((size_t)h * SEQ + tt + row) * 64 + c0);
    u16x8 a = src[0], b = src[1];
#pragma unroll
    for (int j = 0; j < 8; j++) { tile[row][c0 + j] = a[j]; tile[row][c0 + 8 + j] = b[j]; }
    __syncthreads();
    u16x8 o0, o1;
#pragma unroll
    for (int j = 0; j < 8; j++) { o0[j] = tile[c0 + j][row]; o1[j] = tile[c0 + 8 + j][row]; }
    u16x8* dst = (u16x8*)(vT + ((size_t)h * 64 + row) * SEQ + tt + c0);
    dst[0] = o0; dst[1] = o1;
}

// ---------------- causal flash attention ----------------
// block = (head h, q-tile of 64 rows); 4 waves x 16 q-rows; KVBLK = 64
__global__ __launch_bounds__(256) void attn_kernel(
    const unsigned short* __restrict__ qh,   // [16][SEQ][64]
    const unsigned short* __restrict__ kh,   // [16][SEQ][64]
    const unsigned short* __restrict__ vT,   // [16][64][SEQ]
    unsigned short* __restrict__ y)          // [SEQ][1024]
{
    __shared__ __align__(16) unsigned short Ks[64 * 64];
    __shared__ __align__(16) unsigned short Vs[64 * 64];   // [d][kv]
    __shared__ __align__(16) unsigned short Ps[4][16][72];
    const int h = blockIdx.x;
    const int qt = blockIdx.y;
    const int tid = threadIdx.x;
    const int lane = tid & 63;
    const int wave = tid >> 6;
    const int q0 = qt * 64 + wave * 16;
    const int l15 = lane & 15, l4 = lane >> 4;

    const unsigned short* qb = qh + ((size_t)h * SEQ + q0 + l15) * 64 + l4 * 8;
    u16x8 qf0 = *(const u16x8*)qb;
    u16x8 qf1 = *(const u16x8*)(qb + 32);

    f32x4 o[4];
    float mr[4], lr[4];
#pragma unroll
    for (int j = 0; j < 4; j++) o[j] = (f32x4){0.f, 0.f, 0.f, 0.f};
#pragma unroll
    for (int r = 0; r < 4; r++) { mr[r] = -1e30f; lr[r] = 0.f; }

    const unsigned short* Kb = kh + (size_t)h * SEQ * 64;
    const unsigned short* Vb = vT + (size_t)h * 64 * SEQ;

    for (int kt = 0; kt <= qt; kt++) {
        const int kv0 = kt * 64;
        // K tile: 64 rows x 64 d, contiguous 8KB
        gload_lds16(Kb + (size_t)kv0 * 64 + tid * 8, &Ks[tid * 8]);
        gload_lds16(Kb + (size_t)kv0 * 64 + 2048 + tid * 8, &Ks[2048 + tid * 8]);
        // V^T tile: 64 d-rows x 64 kv
        gload_lds16(Vb + (size_t)(tid >> 3) * SEQ + kv0 + (tid & 7) * 8, &Vs[tid * 8]);
        gload_lds16(Vb + (size_t)(32 + (tid >> 3)) * SEQ + kv0 + (tid & 7) * 8, &Vs[2048 + tid * 8]);
        __syncthreads();

        // S = Q K^T * scale  (frag cols nf*16+l15 = kv, rows l4*4+r = q)
        float p[4][4];
#pragma unroll
        for (int nf = 0; nf < 4; nf++) {
            f32x4 s4 = (f32x4){0.f, 0.f, 0.f, 0.f};
            u16x8 kf0 = *(const u16x8*)&Ks[(nf * 16 + l15) * 64 + l4 * 8];
            u16x8 kf1 = *(const u16x8*)&Ks[(nf * 16 + l15) * 64 + 32 + l4 * 8];
            s4 = mfma_bf16_16x16x32(qf0, kf0, s4);
            s4 = mfma_bf16_16x16x32(qf1, kf1, s4);
#pragma unroll
            for (int r = 0; r < 4; r++) p[nf][r] = s4[r] * 0.125f;
        }
        if (kt == qt) {
#pragma unroll
            for (int nf = 0; nf < 4; nf++)
#pragma unroll
                for (int r = 0; r < 4; r++) {
                    int cg = kv0 + nf * 16 + l15;
                    int rg = q0 + l4 * 4 + r;
                    if (cg > rg) p[nf][r] = -1e30f;
                }
        }
        float rm[4], rs[4], fs[4];
#pragma unroll
        for (int r = 0; r < 4; r++)
            rm[r] = fmaxf(fmaxf(p[0][r], p[1][r]), fmaxf(p[2][r], p[3][r]));
#pragma unroll
        for (int m = 1; m < 16; m <<= 1)
#pragma unroll
            for (int r = 0; r < 4; r++) rm[r] = fmaxf(rm[r], __shfl_xor(rm[r], m));
#pragma unroll
        for (int r = 0; r < 4; r++) {
            float mn = fmaxf(mr[r], rm[r]);
            fs[r] = __expf(mr[r] - mn);
            mr[r] = mn;
        }
#pragma unroll
        for (int nf = 0; nf < 4; nf++)
#pragma unroll
            for (int r = 0; r < 4; r++) p[nf][r] = __expf(p[nf][r] - mr[r]);
#pragma unroll
        for (int r = 0; r < 4; r++) rs[r] = p[0][r] + p[1][r] + p[2][r] + p[3][r];
#pragma unroll
        for (int m = 1; m < 16; m <<= 1)
#pragma unroll
            for (int r = 0; r < 4; r++) rs[r] += __shfl_xor(rs[r], m);
#pragma unroll
        for (int r = 0; r < 4; r++) lr[r] = lr[r] * fs[r] + rs[r];
#pragma unroll
        for (int nf = 0; nf < 4; nf++)
#pragma unroll
            for (int r = 0; r < 4; r++) o[nf][r] *= fs[r];
        // repack P (acc layout) -> A-operand layout via per-wave LDS
#pragma unroll
        for (int nf = 0; nf < 4; nf++)
#pragma unroll
            for (int r = 0; r < 4; r++)
                Ps[wave][l4 * 4 + r][nf * 16 + l15] = f2bf(p[nf][r]);
        __syncthreads();
#pragma unroll
        for (int ks = 0; ks < 2; ks++) {
            u16x8 pf = *(const u16x8*)&Ps[wave][l15][ks * 32 + l4 * 8];
#pragma unroll
            for (int nf = 0; nf < 4; nf++) {
                u16x8 vf = *(const u16x8*)&Vs[(nf * 16 + l15) * 64 + ks * 32 + l4 * 8];
                o[nf] = mfma_bf16_16x16x32(pf, vf, o[nf]);
            }
        }
        __syncthreads();
    }
#pragma unroll
    for (int nf = 0; nf < 4; nf++)
#pragma unroll
        for (int r = 0; r < 4; r++) {
            float ov = o[nf][r] / lr[r];
            int rg = q0 + l4 * 4 + r;
            y[(size_t)rg * 1024 + h * 64 + nf * 16 + l15] = f2bf(ov);
        }
}

extern "C" void kernel_launch(void* const* d_in, const int* in_sizes, int n_in,
                              void* d_out, int out_size, void* d_ws, size_t ws_size,
                              hipStream_t stream) {
    (void)in_sizes; (void)n_in; (void)out_size; (void)ws_size;
    const float* x       = (const float*)d_in[0];
    const float* qkv_w   = (const float*)d_in[1];
    const float* lambdas = (const float*)d_in[2];
    const float* proj_w  = (const float*)d_in[3];

    char* ws = (char*)d_ws;
    unsigned short* x_bf   = (unsigned short*)(ws + 0);          //  8 MB  [4096][1024]
    unsigned short* wq_bf  = (unsigned short*)(ws + 8388608);    //  6 MB  [3072][1024]
    unsigned short* wp_bf  = (unsigned short*)(ws + 14680064);   //  2 MB  [1024][1024]
    unsigned short* qkv_bf = (unsigned short*)(ws + 16777216);   // 24 MB  [4096][3072]
    unsigned short* qh     = (unsigned short*)(ws + 41943040);   //  8 MB  [16][4096][64]
    unsigned short* kh     = (unsigned short*)(ws + 50331648);   //  8 MB
    unsigned short* vh     = (unsigned short*)(ws + 58720256);   //  8 MB
    unsigned short* vT     = (unsigned short*)(ws + 67108864);   //  8 MB  [16][64][4096]
    unsigned short* yb     = (unsigned short*)(ws + 75497472);   //  8 MB  [4096][1024]

    cvt_kernel<<<1024, 256, 0, stream>>>(x, x_bf, 4194304);
    cvt_kernel<<<1024, 256, 0, stream>>>(qkv_w, wq_bf, 3145728);
    cvt_kernel<<<512, 256, 0, stream>>>(proj_w, wp_bf, 1048576);

    gemm_bt_kernel<1><<<dim3(24, 32), 256, 0, stream>>>(x_bf, wq_bf, qkv_bf, 4096, 3072, 1024, 1024);
    rope_norm_kernel<<<16384, 256, 0, stream>>>(qkv_bf, lambdas, qh, kh, vh);
    transpose_v_kernel<<<1024, 256, 0, stream>>>(vh, vT);
    attn_kernel<<<dim3(16, 64), 256, 0, stream>>>(qh, kh, vT, yb);
    gemm_bt_kernel<0><<<dim3(8, 32), 256, 0, stream>>>(yb, wp_bf, d_out, 4096, 1024, 1024, 1024);
}

// Round 2
// 227.669 us; speedup vs baseline: 1.3188x; 1.3188x over previous
//
#include <hip/hip_runtime.h>
#include <stdint.h>

#define SEQ 4096
#define NHEAD 16
#define HDIM 64

typedef __attribute__((ext_vector_type(4))) float f32x4;
typedef __attribute__((ext_vector_type(8))) __bf16 bf16x8;
typedef __attribute__((ext_vector_type(8))) unsigned short u16x8;
typedef __attribute__((ext_vector_type(4))) unsigned short u16x4;

static __device__ __forceinline__ float bf2f(unsigned short u) {
    unsigned int x = ((unsigned int)u) << 16;
    return __builtin_bit_cast(float, x);
}
static __device__ __forceinline__ unsigned short f2bf(float f) {
    unsigned int u = __builtin_bit_cast(unsigned int, f);
    u += 0x7FFFu + ((u >> 16) & 1u);   // RNE
    return (unsigned short)(u >> 16);
}
static __device__ __forceinline__ f32x4 mfma_bf16_16x16x32(u16x8 a, u16x8 b, f32x4 c) {
    return __builtin_amdgcn_mfma_f32_16x16x32_bf16(
        __builtin_bit_cast(bf16x8, a), __builtin_bit_cast(bf16x8, b), c, 0, 0, 0);
}
static __device__ __forceinline__ void gload_lds16(const void* g, void* l) {
    __builtin_amdgcn_global_load_lds(
        (__attribute__((address_space(1))) unsigned int*)g,
        (__attribute__((address_space(3))) unsigned int*)l,
        16, 0, 0);
}

// ---------------- f32 -> bf16 convert ----------------
__global__ void cvt_kernel(const float* __restrict__ src, unsigned short* __restrict__ dst, int n) {
    const int stride = gridDim.x * blockDim.x;
    for (int i = blockIdx.x * blockDim.x + threadIdx.x; i * 4 < n; i += stride) {
        f32x4 v = *(const f32x4*)(src + (size_t)i * 4);
        u16x4 o;
#pragma unroll
        for (int j = 0; j < 4; j++) o[j] = f2bf(v[j]);
        *(u16x4*)(dst + (size_t)i * 4) = o;
    }
}

// ---------------- GEMM: C[M][N] = A[M][K(lda)] * B[N][K]^T ----------------
// 128x128 tile, BK=64, 256 threads = 4 waves (2x2), each wave 64x64 (4x4 frags)
template<int OUT_BF16>
__global__ __launch_bounds__(256) void gemm_bt_kernel(
    const unsigned short* __restrict__ A,
    const unsigned short* __restrict__ B,
    void* __restrict__ Cv,
    int M, int N, int K, int lda)
{
    __shared__ __align__(16) unsigned short As[128 * 64];
    __shared__ __align__(16) unsigned short Bs[128 * 64];
    const int tid = threadIdx.x;
    const int lane = tid & 63;
    const int wave = tid >> 6;
    const int wm = (wave >> 1) * 64;
    const int wn = (wave & 1) * 64;
    const int bm = blockIdx.y * 128, bn = blockIdx.x * 128;
    const int l15 = lane & 15, l4 = lane >> 4;

    f32x4 acc[4][4];
#pragma unroll
    for (int i = 0; i < 4; i++)
#pragma unroll
        for (int j = 0; j < 4; j++) acc[i][j] = (f32x4){0.f, 0.f, 0.f, 0.f};

    const int srow = tid >> 3;
    const int scol = (tid & 7) * 8;
    const unsigned short* Ab = A + (size_t)(bm + srow) * lda + scol;
    const unsigned short* Bb = B + (size_t)(bn + srow) * K + scol;

    for (int kt = 0; kt < K; kt += 64) {
#pragma unroll
        for (int ci = 0; ci < 4; ci++)
            gload_lds16(Ab + (size_t)ci * 32 * lda + kt, &As[ci * 2048 + tid * 8]);
#pragma unroll
        for (int ci = 0; ci < 4; ci++)
            gload_lds16(Bb + (size_t)ci * 32 * K + kt, &Bs[ci * 2048 + tid * 8]);
        __syncthreads();
#pragma unroll
        for (int ks = 0; ks < 2; ks++) {
            const int kc = ks * 32 + l4 * 8;
            u16x8 af[4], bfr[4];
#pragma unroll
            for (int i = 0; i < 4; i++)
                af[i] = *(const u16x8*)&As[(wm + i * 16 + l15) * 64 + kc];
#pragma unroll
            for (int j = 0; j < 4; j++)
                bfr[j] = *(const u16x8*)&Bs[(wn + j * 16 + l15) * 64 + kc];
#pragma unroll
            for (int i = 0; i < 4; i++)
#pragma unroll
                for (int j = 0; j < 4; j++)
                    acc[i][j] = mfma_bf16_16x16x32(af[i], bfr[j], acc[i][j]);
        }
        __syncthreads();
    }

    const int orow = bm + wm + l4 * 4;
    const int ocol = bn + wn + l15;
#pragma unroll
    for (int i = 0; i < 4; i++)
#pragma unroll
        for (int j = 0; j < 4; j++)
#pragma unroll
            for (int r = 0; r < 4; r++) {
                size_t idx = (size_t)(orow + i * 16 + r) * N + (ocol + j * 16);
                if (OUT_BF16) ((unsigned short*)Cv)[idx] = f2bf(acc[i][j][r]);
                else          ((float*)Cv)[idx] = acc[i][j][r];
            }
}

// ---------------- RMS-norm + RoPE + lambda*v ----------------
// one wave = one (t, h) vector of 64 dims; lane = d
// Q additionally pre-scaled by 1/sqrt(D) so attention skips the scale.
__global__ __launch_bounds__(256) void rope_norm_kernel(
    const unsigned short* __restrict__ qkv,   // [SEQ][3072] bf16
    const float* __restrict__ lambdas,
    unsigned short* __restrict__ qh,          // [16][SEQ][64]
    unsigned short* __restrict__ kh,
    unsigned short* __restrict__ vh)
{
    const int lane = threadIdx.x & 63;
    const int wave = threadIdx.x >> 6;
    const int vec = blockIdx.x * 4 + wave;
    const int t = vec >> 4;
    const int h = vec & 15;
    const size_t base = (size_t)t * 3072 + h * 64 + lane;
    float q = bf2f(qkv[base]);
    float k = bf2f(qkv[base + 1024]);
    float v = bf2f(qkv[base + 2048]);
    float sq = q * q, sk = k * k;
#pragma unroll
    for (int m = 1; m < 64; m <<= 1) {
        sq += __shfl_xor(sq, m);
        sk += __shfl_xor(sk, m);
    }
    q *= rsqrtf(sq * (1.0f / 64.0f) + 1e-6f);
    k *= rsqrtf(sk * (1.0f / 64.0f) + 1e-6f);
    const int i = lane & 31;
    // (1/1024)^(i/15) = 2^(-10i/15); zero freq (identity) for i >= 16
    float w = (i < 16) ? exp2f(-(10.0f / 15.0f) * (float)i) : 0.0f;
    float th = (float)t * w;
    float c = cosf(th), s = sinf(th);
    float qp = __shfl_xor(q, 32);
    float kp = __shfl_xor(k, 32);
    float sg = (lane < 32) ? s : -s;   // y1 = x1*c + x2*s ; y2 = x2*c - x1*s
    float qo = (q * c + qp * sg) * 0.125f;   // fold in 1/sqrt(64)
    float ko = k * c + kp * sg;
    float vo = v * lambdas[0];
    const size_t o = ((size_t)h * SEQ + t) * 64 + lane;
    qh[o] = f2bf(qo);
    kh[o] = f2bf(ko);
    vh[o] = f2bf(vo);
}

// ---------------- V transpose: [h][t][d] -> [h][d][t] ----------------
__global__ __launch_bounds__(256) void transpose_v_kernel(
    const unsigned short* __restrict__ vh, unsigned short* __restrict__ vT)
{
    __shared__ __align__(16) unsigned short tile[64][72];
    const int h = blockIdx.x >> 6;
    const int tt = (blockIdx.x & 63) * 64;
    const int tid = threadIdx.x;
    const int row = tid >> 2;          // 0..63
    const int c0 = (tid & 3) * 16;     // 0,16,32,48
    const u16x8* src = (const u16x8*)(vh + ((size_t)h * SEQ + tt + row) * 64 + c0);
    u16x8 a = src[0], b = src[1];
#pragma unroll
    for (int j = 0; j < 8; j++) { tile[row][c0 + j] = a[j]; tile[row][c0 + 8 + j] = b[j]; }
    __syncthreads();
    u16x8 o0, o1;
#pragma unroll
    for (int j = 0; j < 8; j++) { o0[j] = tile[c0 + j][row]; o1[j] = tile[c0 + 8 + j][row]; }
    u16x8* dst = (u16x8*)(vT + ((size_t)h * 64 + row) * SEQ + tt + c0);
    dst[0] = o0; dst[1] = o1;
}

// ---------------- causal flash attention ----------------
// block = (head h, q-tile of 64 rows); 4 waves x 16 q-rows; KVBLK = 64
// - K/V LDS tiles XOR-swizzled at 16B-chunk granularity (chunk ^= row&7);
//   staging keeps the LDS destination linear (global_load_lds requirement)
//   and applies the inverse permutation on the per-lane GLOBAL source.
// - double-buffered staging, 1 barrier per KV tile (pre-barrier waitcnt
//   drain is the staging wait).
// - heavy-first: qt reversed so longest blocks dispatch first.
__global__ __launch_bounds__(256) void attn_kernel(
    const unsigned short* __restrict__ qh,   // [16][SEQ][64], pre-scaled
    const unsigned short* __restrict__ kh,   // [16][SEQ][64]
    const unsigned short* __restrict__ vT,   // [16][64][SEQ]
    unsigned short* __restrict__ y)          // [SEQ][1024]
{
    __shared__ __align__(16) unsigned short Ks[2][64 * 64];
    __shared__ __align__(16) unsigned short Vs[2][64 * 64];   // [d][kv]
    __shared__ __align__(16) unsigned short Ps[4][16][72];
    const int h = blockIdx.x;
    const int qt = (int)gridDim.y - 1 - blockIdx.y;   // heavy blocks first
    const int tid = threadIdx.x;
    const int lane = tid & 63;
    const int wave = tid >> 6;
    const int q0 = qt * 64 + wave * 16;
    const int l15 = lane & 15, l4 = lane >> 4;
    const int sw = (l15 & 7) * 8;          // read-side swizzle (rows R: R&7 == l15&7)

    const unsigned short* Kb = kh + (size_t)h * SEQ * 64;
    const unsigned short* Vb = vT + (size_t)h * 64 * SEQ;

    // staging geometry: lane tid fills LDS shorts [tid*8, tid*8+8) (linear);
    // source chunk is inverse-swizzled.
    const int sr = tid >> 3;               // row 0..31 (+32 for second call)
    const int scs = ((tid & 7) * 8) ^ ((sr & 7) * 8);

    const unsigned short* qb = qh + ((size_t)h * SEQ + q0 + l15) * 64 + l4 * 8;
    u16x8 qf0 = *(const u16x8*)qb;
    u16x8 qf1 = *(const u16x8*)(qb + 32);

    f32x4 o[4];
    float mr[4], lr[4];
#pragma unroll
    for (int j = 0; j < 4; j++) o[j] = (f32x4){0.f, 0.f, 0.f, 0.f};
#pragma unroll
    for (int r = 0; r < 4; r++) { mr[r] = -1e30f; lr[r] = 0.f; }

    // prologue: stage tile 0 into buffer 0
    gload_lds16(Kb + (size_t)sr * 64 + scs,            &Ks[0][tid * 8]);
    gload_lds16(Kb + (size_t)(32 + sr) * 64 + scs,     &Ks[0][2048 + tid * 8]);
    gload_lds16(Vb + (size_t)sr * SEQ + scs,           &Vs[0][tid * 8]);
    gload_lds16(Vb + (size_t)(32 + sr) * SEQ + scs,    &Vs[0][2048 + tid * 8]);
    __syncthreads();

    int cur = 0;
    for (int kt = 0; kt <= qt; kt++) {
        const int kv0 = kt * 64;
        if (kt < qt) {   // prefetch next tile into the other buffer
            const int nkv = kv0 + 64;
            gload_lds16(Kb + (size_t)(nkv + sr) * 64 + scs,        &Ks[cur ^ 1][tid * 8]);
            gload_lds16(Kb + (size_t)(nkv + 32 + sr) * 64 + scs,   &Ks[cur ^ 1][2048 + tid * 8]);
            gload_lds16(Vb + (size_t)sr * SEQ + nkv + scs,         &Vs[cur ^ 1][tid * 8]);
            gload_lds16(Vb + (size_t)(32 + sr) * SEQ + nkv + scs,  &Vs[cur ^ 1][2048 + tid * 8]);
        }
        const unsigned short* ksb = Ks[cur];
        const unsigned short* vsb = Vs[cur];

        // S = Q K^T (frag cols nf*16+l15 = kv, rows l4*4+r = q); Q pre-scaled
        float p[4][4];
#pragma unroll
        for (int nf = 0; nf < 4; nf++) {
            const int R = nf * 16 + l15;
            f32x4 s4 = (f32x4){0.f, 0.f, 0.f, 0.f};
            u16x8 kf0 = *(const u16x8*)&ksb[R * 64 + ((l4 * 8) ^ sw)];
            u16x8 kf1 = *(const u16x8*)&ksb[R * 64 + ((32 + l4 * 8) ^ sw)];
            s4 = mfma_bf16_16x16x32(qf0, kf0, s4);
            s4 = mfma_bf16_16x16x32(qf1, kf1, s4);
#pragma unroll
            for (int r = 0; r < 4; r++) p[nf][r] = s4[r];
        }
        if (kt == qt) {
#pragma unroll
            for (int nf = 0; nf < 4; nf++)
#pragma unroll
                for (int r = 0; r < 4; r++) {
                    int cg = kv0 + nf * 16 + l15;
                    int rg = q0 + l4 * 4 + r;
                    if (cg > rg) p[nf][r] = -1e30f;
                }
        }
        float rm[4], rs[4], fs[4];
#pragma unroll
        for (int r = 0; r < 4; r++)
            rm[r] = fmaxf(fmaxf(p[0][r], p[1][r]), fmaxf(p[2][r], p[3][r]));
#pragma unroll
        for (int m = 1; m < 16; m <<= 1)
#pragma unroll
            for (int r = 0; r < 4; r++) rm[r] = fmaxf(rm[r], __shfl_xor(rm[r], m));
#pragma unroll
        for (int r = 0; r < 4; r++) {
            float mn = fmaxf(mr[r], rm[r]);
            fs[r] = __expf(mr[r] - mn);
            mr[r] = mn;
        }
#pragma unroll
        for (int nf = 0; nf < 4; nf++)
#pragma unroll
            for (int r = 0; r < 4; r++) p[nf][r] = __expf(p[nf][r] - mr[r]);
#pragma unroll
        for (int r = 0; r < 4; r++) rs[r] = p[0][r] + p[1][r] + p[2][r] + p[3][r];
#pragma unroll
        for (int m = 1; m < 16; m <<= 1)
#pragma unroll
            for (int r = 0; r < 4; r++) rs[r] += __shfl_xor(rs[r], m);
#pragma unroll
        for (int r = 0; r < 4; r++) lr[r] = lr[r] * fs[r] + rs[r];
#pragma unroll
        for (int nf = 0; nf < 4; nf++)
#pragma unroll
            for (int r = 0; r < 4; r++) o[nf][r] *= fs[r];

        // repack P (acc layout) -> A-operand layout via per-wave LDS.
        // Per-wave buffer: write->read needs only lgkmcnt (compiler-inserted),
        // no barrier.
#pragma unroll
        for (int nf = 0; nf < 4; nf++)
#pragma unroll
            for (int r = 0; r < 4; r++)
                Ps[wave][l4 * 4 + r][nf * 16 + l15] = f2bf(p[nf][r]);
#pragma unroll
        for (int ks = 0; ks < 2; ks++) {
            u16x8 pf = *(const u16x8*)&Ps[wave][l15][ks * 32 + l4 * 8];
#pragma unroll
            for (int nf = 0; nf < 4; nf++) {
                const int R = nf * 16 + l15;
                u16x8 vf = *(const u16x8*)&vsb[R * 64 + ((ks * 32 + l4 * 8) ^ sw)];
                o[nf] = mfma_bf16_16x16x32(pf, vf, o[nf]);
            }
        }
        // single barrier per tile: compiler drains vmcnt (prefetch) +
        // lgkmcnt before s_barrier; afterwards cur^1 holds tile kt+1 and
        // everyone is done reading cur.
        __syncthreads();
        cur ^= 1;
    }
#pragma unroll
    for (int nf = 0; nf < 4; nf++)
#pragma unroll
        for (int r = 0; r < 4; r++) {
            float ov = o[nf][r] / lr[r];
            int rg = q0 + l4 * 4 + r;
            y[(size_t)rg * 1024 + h * 64 + nf * 16 + l15] = f2bf(ov);
        }
}

extern "C" void kernel_launch(void* const* d_in, const int* in_sizes, int n_in,
                              void* d_out, int out_size, void* d_ws, size_t ws_size,
                              hipStream_t stream) {
    (void)in_sizes; (void)n_in; (void)out_size; (void)ws_size;
    const float* x       = (const float*)d_in[0];
    const float* qkv_w   = (const float*)d_in[1];
    const float* lambdas = (const float*)d_in[2];
    const float* proj_w  = (const float*)d_in[3];

    char* ws = (char*)d_ws;
    unsigned short* x_bf   = (unsigned short*)(ws + 0);          //  8 MB  [4096][1024]
    unsigned short* wq_bf  = (unsigned short*)(ws + 8388608);    //  6 MB  [3072][1024]
    unsigned short* wp_bf  = (unsigned short*)(ws + 14680064);   //  2 MB  [1024][1024]
    unsigned short* qkv_bf = (unsigned short*)(ws + 16777216);   // 24 MB  [4096][3072]
    unsigned short* qh     = (unsigned short*)(ws + 41943040);   //  8 MB  [16][4096][64]
    unsigned short* kh     = (unsigned short*)(ws + 50331648);   //  8 MB
    unsigned short* vh     = (unsigned short*)(ws + 58720256);   //  8 MB
    unsigned short* vT     = (unsigned short*)(ws + 67108864);   //  8 MB  [16][64][4096]
    unsigned short* yb     = (unsigned short*)(ws + 75497472);   //  8 MB  [4096][1024]

    cvt_kernel<<<1024, 256, 0, stream>>>(x, x_bf, 4194304);
    cvt_kernel<<<1024, 256, 0, stream>>>(qkv_w, wq_bf, 3145728);
    cvt_kernel<<<512, 256, 0, stream>>>(proj_w, wp_bf, 1048576);

    gemm_bt_kernel<1><<<dim3(24, 32), 256, 0, stream>>>(x_bf, wq_bf, qkv_bf, 4096, 3072, 1024, 1024);
    rope_norm_kernel<<<16384, 256, 0, stream>>>(qkv_bf, lambdas, qh, kh, vh);
    transpose_v_kernel<<<1024, 256, 0, stream>>>(vh, vT);
    attn_kernel<<<dim3(16, 64), 256, 0, stream>>>(qh, kh, vT, yb);
    gemm_bt_kernel<0><<<dim3(8, 32), 256, 0, stream>>>(yb, wp_bf, d_out, 4096, 1024, 1024, 1024);
}